// Round 1
// 313.361 us; speedup vs baseline: 1.0084x; 1.0084x over previous
//
#include <hip/hip_runtime.h>
#include <math.h>

// ---------------- problem constants ----------------
#define T_LEN   1024
#define HIDDEN  2048
#define QKVZ_N  6144   // 2*KEY_DIM + 2*VALUE_DIM
#define VAL_DIM 2048

typedef _Float16 half8 __attribute__((ext_vector_type(8)));
typedef _Float16 half4 __attribute__((ext_vector_type(4)));
typedef _Float16 half2t __attribute__((ext_vector_type(2)));
typedef float floatx4 __attribute__((ext_vector_type(4)));

__device__ __forceinline__ float sigmoidf_(float x) { return 1.f / (1.f + expf(-x)); }

// async global->LDS, 16B per lane; LDS dest = wave-uniform base + lane*16
__device__ __forceinline__ void gl_lds16(const _Float16* g, _Float16* l) {
    __builtin_amdgcn_global_load_lds(
        (const __attribute__((address_space(1))) void*)g,
        (__attribute__((address_space(3))) void*)l, 16, 0, 0);
}

// ---------------------------------------------------------------------------
// fused fp32 -> fp16 bulk convert of the three GEMM operands (1 launch)
// ---------------------------------------------------------------------------
__global__ __launch_bounds__(256) void cvt3(const float* __restrict__ s0, _Float16* __restrict__ d0, int n0,
                                            const float* __restrict__ s1, _Float16* __restrict__ d1, int n1,
                                            const float* __restrict__ s2, _Float16* __restrict__ d2, int n2) {
    int i = blockIdx.x * 256 + threadIdx.x;
    const float* s;
    _Float16* d;
    if (i < n0) { s = s0; d = d0; }
    else if (i < n0 + n1) { s = s1; d = d1; i -= n0; }
    else if (i < n0 + n1 + n2) { s = s2; d = d2; i -= n0 + n1; }
    else return;
    const float4 v = ((const float4*)s)[i];
    half4 h;
    h[0] = (_Float16)v.x; h[1] = (_Float16)v.y;
    h[2] = (_Float16)v.z; h[3] = (_Float16)v.w;
    *(half4*)&d[i * 4] = h;
}

// ---------------------------------------------------------------------------
// Pure-fp16 MFMA GEMM, async-staged: C[M,N] = A[M,K]*W[N,K]^T.
// 64x128 tile, BK=32, 4 waves 2x2 (each 32x64 = 2x4 frags of 16x16x32).
//   qkvz GEMM: 16x48 = 768 blocks = exactly 3/CU (balanced; was 384 = 1.5/CU)
//   out  GEMM: 16x16 = 256 blocks = exactly 1/CU (balanced; was 128 = 0.5/CU)
// Staging via global_load_lds width=16; per-lane global k-chunk permuted with
// key(r) = (r ^ (r>>2)) & 3 so the async lane->slot mapping reproduces the
// XOR-swizzled layout the frag reads expect.  Key has period 8 over rows ->
// the 16 same-quad lanes of a ds_read_b128 hit all 8 bank-groups 2x each
// (2-way = free, m136).  The previous key (r&3) had period 4 -> 4 groups x 4
// lanes = 4-way conflict (measured: exactly 4 extra cycles per ds_read).
// XCD swizzle: all m-blocks of one n-block share blockIdx%8 -> same XCD L2.
// ---------------------------------------------------------------------------
template <typename OutT>
__global__ __launch_bounds__(256, 2) void gemm_h16(const _Float16* __restrict__ A,
                                                   const _Float16* __restrict__ W,
                                                   OutT* __restrict__ C,
                                                   int MB, int NB, int K) {
    const int N = NB * 128;
    const int l = blockIdx.x;
    const int x = l & 7;
    const int tt = l >> 3;
    const int mb = tt % MB;
    const int nb = x + 8 * (tt / MB);
    const int m0 = mb * 64, n0 = nb * 128;

    const int t = threadIdx.x;
    const int wave = t >> 6;
    const int lane = t & 63;
    const int wr = (wave >> 1) * 32;   // wave row offset (2 wave-rows of 32)
    const int wc = (wave & 1) * 64;    // wave col offset (2 wave-cols of 64)
    const int l15 = lane & 15;
    const int quad = lane >> 4;

    __shared__ __align__(16) _Float16 Ah[2048];  //  64 rows x 32 k, swizzled
    __shared__ __align__(16) _Float16 Bh[4096];  // 128 rows x 32 k, swizzled

    // staging coords: lane -> (row within wave's 16-row strip, k-chunk)
    const int sr = lane >> 2;        // 0..15
    const int skq = lane & 3;        // slot k index

    floatx4 acc[2][4];
#pragma unroll
    for (int i = 0; i < 2; ++i)
#pragma unroll
        for (int j = 0; j < 4; ++j) acc[i][j] = 0;

    for (int k0 = 0; k0 < K; k0 += 32) {
        __syncthreads();   // previous iteration's frag reads done
        {
            // A: 64 rows, one gl_lds16 per wave
            const int r = wave * 16 + sr;
            const int kc = skq ^ ((r ^ (r >> 2)) & 3);   // permuted global chunk
            gl_lds16(A + (size_t)(m0 + r) * K + k0 + kc * 8, &Ah[wave * 512]);
        }
#pragma unroll
        for (int p = 0; p < 2; ++p) {
            // B: 128 rows, two gl_lds16 per wave
            const int r = p * 64 + wave * 16 + sr;
            const int kc = skq ^ ((r ^ (r >> 2)) & 3);
            gl_lds16(W + (size_t)(n0 + r) * K + k0 + kc * 8, &Bh[p * 2048 + wave * 512]);
        }
        __syncthreads();   // drains vmcnt (compiler emits s_waitcnt vmcnt(0))
        half8 af[2], bf[4];
#pragma unroll
        for (int mt = 0; mt < 2; ++mt) {
            const int m = wr + mt * 16 + l15;
            af[mt] = *(const half8*)&Ah[(m * 4 + (quad ^ ((m ^ (m >> 2)) & 3))) * 8];
        }
#pragma unroll
        for (int nt = 0; nt < 4; ++nt) {
            const int n = wc + nt * 16 + l15;
            bf[nt] = *(const half8*)&Bh[(n * 4 + (quad ^ ((n ^ (n >> 2)) & 3))) * 8];
        }
#pragma unroll
        for (int mt = 0; mt < 2; ++mt)
#pragma unroll
            for (int nt = 0; nt < 4; ++nt)
                acc[mt][nt] = __builtin_amdgcn_mfma_f32_16x16x32_f16(
                    af[mt], bf[nt], acc[mt][nt], 0, 0, 0);
    }
#pragma unroll
    for (int mt = 0; mt < 2; ++mt)
#pragma unroll
        for (int nt = 0; nt < 4; ++nt) {
            const int c = n0 + wc + nt * 16 + l15;
#pragma unroll
            for (int reg = 0; reg < 4; ++reg) {
                const int r = m0 + wr + mt * 16 + quad * 4 + reg;
                C[(size_t)r * N + c] = (OutT)acc[mt][nt][reg];
            }
        }
}

// ---------------------------------------------------------------------------
// ba projection fused with gates: per row m compute ba[32] in-block, then
// beta = sigmoid(b), lgd = -exp(A_log)*softplus(a+dt_bias).  1024 blocks.
// ---------------------------------------------------------------------------
__global__ __launch_bounds__(256) void gemm_ba_gates(const float* __restrict__ A,
                                                     const float* __restrict__ W,
                                                     const float* __restrict__ dt_bias,
                                                     const float* __restrict__ A_log,
                                                     float* __restrict__ lgd,
                                                     float* __restrict__ bet) {
    const int m = blockIdx.x;
    const int tid = threadIdx.x;
    const int kl = tid & 31;
    const int ng = tid >> 5;
    const float* Arow = A + (size_t)m * 2048;
    __shared__ float sba[32];

    float4 a4[16];
#pragma unroll
    for (int j = 0; j < 16; ++j)
        a4[j] = *(const float4*)(Arow + j * 128 + kl * 4);

#pragma unroll
    for (int nn = 0; nn < 4; ++nn) {
        const int n = nn * 8 + ng;
        const float* Wrow = W + (size_t)n * 2048;
        float acc = 0.f;
#pragma unroll
        for (int j = 0; j < 16; ++j) {
            const float4 w4 = *(const float4*)(Wrow + j * 128 + kl * 4);
            acc = fmaf(a4[j].x, w4.x, acc);
            acc = fmaf(a4[j].y, w4.y, acc);
            acc = fmaf(a4[j].z, w4.z, acc);
            acc = fmaf(a4[j].w, w4.w, acc);
        }
        acc += __shfl_xor(acc, 1, 64);
        acc += __shfl_xor(acc, 2, 64);
        acc += __shfl_xor(acc, 4, 64);
        acc += __shfl_xor(acc, 8, 64);
        acc += __shfl_xor(acc, 16, 64);
        if (kl == 0) sba[n] = acc;
    }
    __syncthreads();
    if (tid < 16) {
        const int vh = tid, kh = vh >> 1, r = vh & 1;
        const float b = sba[kh * 4 + r];
        const float a = sba[kh * 4 + 2 + r];
        bet[m * 16 + vh] = 1.f / (1.f + expf(-b));
        const float xx = a + dt_bias[vh];
        const float sp = (xx > 0.f) ? (xx + log1pf(expf(-xx))) : log1pf(expf(xx));
        lgd[m * 16 + vh] = -expf(A_log[vh]) * sp;
    }
}

// ---------------------------------------------------------------------------
// Depthwise causal conv1d (K=4) + SiLU + fused q/k L2-norm.
// One 512-thread block per timestep t; thread handles 8 consecutive channels
// (half8 loads per tap -- was 4 scalar 2B loads/thread).  q/k heads are 128
// channels = 16 consecutive lanes (wave-aligned), so the L2-norm reduce is a
// 4-level __shfl_xor; the 128^-0.5 q-scale is folded in.  Replaces the old
// conv_silu + l2norm_qk pair (one fewer dispatch, no q/k 8MB round-trip).
// qkvz row layout per k-head block of 768: [q 128 | k 128 | v 256 | z 256]
// ---------------------------------------------------------------------------
__global__ __launch_bounds__(512) void conv_silu_l2(const _Float16* __restrict__ qkvz,
                                                    const float* __restrict__ conv_w,
                                                    _Float16* __restrict__ qc,
                                                    _Float16* __restrict__ kc,
                                                    _Float16* __restrict__ vc) {
    const int t = blockIdx.x;                 // timestep (uniform per block)
    const int c = threadIdx.x * 8;            // base channel, 0..4088
    int col;
    _Float16* dst;
    bool isqk;
    float extra = 1.f;
    if (c < 1024) {
        col = ((c >> 7) * 768) + (c & 127);
        dst = qc + t * 1024 + c;
        isqk = true;
        extra = 0.08838834764831845f;         // 128^-0.5 folded into q
    } else if (c < 2048) {
        const int cc = c - 1024;
        col = ((cc >> 7) * 768) + 128 + (cc & 127);
        dst = kc + t * 1024 + cc;
        isqk = true;
    } else {
        const int cc = c - 2048;
        col = ((cc >> 8) * 768) + 256 + (cc & 255);
        dst = vc + (size_t)t * 2048 + cc;
        isqk = false;
    }
    const size_t gb = (size_t)t * QKVZ_N + col;
    const half8 x3 = *(const half8*)(qkvz + gb);
    half8 x2, x1, x0;
    if (t >= 1) x2 = *(const half8*)(qkvz + gb - QKVZ_N);
    if (t >= 2) x1 = *(const half8*)(qkvz + gb - 2 * (size_t)QKVZ_N);
    if (t >= 3) x0 = *(const half8*)(qkvz + gb - 3 * (size_t)QKVZ_N);

    float y[8];
    float ss = 0.f;
#pragma unroll
    for (int u = 0; u < 8; ++u) {
        const float4 wv = *(const float4*)(conv_w + (c + u) * 4);
        float acc = (float)x3[u] * wv.w;
        if (t >= 1) acc = fmaf((float)x2[u], wv.z, acc);
        if (t >= 2) acc = fmaf((float)x1[u], wv.y, acc);
        if (t >= 3) acc = fmaf((float)x0[u], wv.x, acc);
        acc = acc * (1.f / (1.f + expf(-acc)));   // silu
        y[u] = acc;
        ss = fmaf(acc, acc, ss);
    }
    half8 ov;
    if (isqk) {
        // head = 128 channels = 16 lanes (lane groups aligned within wave)
        ss += __shfl_xor(ss, 1, 64);
        ss += __shfl_xor(ss, 2, 64);
        ss += __shfl_xor(ss, 4, 64);
        ss += __shfl_xor(ss, 8, 64);
        const float r = rsqrtf(ss + 1e-6f) * extra;
#pragma unroll
        for (int u = 0; u < 8; ++u) ov[u] = (_Float16)(y[u] * r);
    } else {
#pragma unroll
        for (int u = 0; u < 8; ++u) ov[u] = (_Float16)y[u];
    }
    *(half8*)dst = ov;
}

// ---------------------------------------------------------------------------
// chunk_prep (unchanged): per (chunk c, v-head h), fully parallel (256 blocks)
// ---------------------------------------------------------------------------
__global__ __launch_bounds__(256) void chunk_prep(
    const _Float16* __restrict__ qch, const _Float16* __restrict__ kch,
    const _Float16* __restrict__ vch, const float* __restrict__ lgd,
    const float* __restrict__ bet, _Float16* __restrict__ CH,
    float* __restrict__ gamC) {
    const int blk = blockIdx.x;
    const int c = blk >> 4, h = blk & 15, kh = h >> 1;
    const int c0 = c * 64;
    const int tid = threadIdx.x, lane = tid & 63, wave = tid >> 6;
    const int l15 = lane & 15, quad = lane >> 4;

    __shared__ __align__(16) _Float16 Ksh[8192];
    __shared__ __align__(16) _Float16 Qsh[8192];
    __shared__ float Amat[64 * 65];
    __shared__ float Gs[64], Bets[64], Gam[64];

    {
        const int t = tid >> 2, kc0 = (tid & 3) * 4;
        const size_t gb = (size_t)(c0 + t) * 1024 + kh * 128;
#pragma unroll
        for (int i = 0; i < 4; ++i) {
            const int kc = kc0 + i;
            half8 kv = *(const half8*)(kch + gb + kc * 8);
            half8 qv = *(const half8*)(qch + gb + kc * 8);
            const int chl = t * 16 + (kc ^ (t & 15));
            *(half8*)&Ksh[chl * 8] = kv;
            *(half8*)&Qsh[chl * 8] = qv;
        }
    }
    if (tid < 64) {
        float g = lgd[(size_t)(c0 + tid) * 16 + h];
#pragma unroll
        for (int off = 1; off < 64; off <<= 1) {
            float y = __shfl_up(g, off, 64);
            if (tid >= off) g += y;
        }
        Gs[tid] = g;
        Gam[tid] = expf(g);
        Bets[tid] = bet[(size_t)(c0 + tid) * 16 + h];
    }
    __syncthreads();

    _Float16* CHb = CH + (size_t)(c * 16 + h) * 36864;
    _Float16* Ug = CHb;
    _Float16* Wtg = CHb + 8192;
    _Float16* Khg = CHb + 16384;
    _Float16* Qgg = CHb + 24576;
    _Float16* Lg = CHb + 32768;

    {
        floatx4 accKK[4], accQK[4];
#pragma unroll
        for (int tt = 0; tt < 4; ++tt) { accKK[tt] = 0; accQK[tt] = 0; }
        half8 bfK[4];
#pragma unroll
        for (int ks = 0; ks < 4; ++ks) {
            const int i = wave * 16 + l15;
            const int kc = ks * 4 + quad;
            bfK[ks] = *(const half8*)&Ksh[(i * 16 + (kc ^ (i & 15))) * 8];
        }
#pragma unroll
        for (int tt = 0; tt < 4; ++tt) {
            const int t = tt * 16 + l15;
#pragma unroll
            for (int ks = 0; ks < 4; ++ks) {
                const int kc = ks * 4 + quad;
                const int chl = (t * 16 + (kc ^ (t & 15))) * 8;
                half8 afK = *(const half8*)&Ksh[chl];
                half8 afQ = *(const half8*)&Qsh[chl];
                accKK[tt] = __builtin_amdgcn_mfma_f32_16x16x32_f16(afK, bfK[ks], accKK[tt], 0, 0, 0);
                accQK[tt] = __builtin_amdgcn_mfma_f32_16x16x32_f16(afQ, bfK[ks], accQK[tt], 0, 0, 0);
            }
        }
        const int ii = wave * 16 + l15;
        const float Gi = Gs[ii];
#pragma unroll
        for (int tt = 0; tt < 4; ++tt)
#pragma unroll
            for (int r = 0; r < 4; ++r) {
                const int t = tt * 16 + quad * 4 + r;
                const float Gt = Gs[t];
                const float ratio = (ii <= t) ? expf(Gt - Gi) : 0.f;
                if (ii < t) Amat[t * 65 + ii] = Bets[t] * ratio * accKK[tt][r];
                Lg[t * 64 + ii] = (_Float16)((ii <= t) ? ratio * accQK[tt][r] : 0.f);
            }
    }
    __syncthreads();

    {
        const int j = tid;
        float x[64];
        if (j < 128) {
#pragma unroll
            for (int t = 0; t < 64; ++t)
                x[t] = Bets[t] * (float)vch[(size_t)(c0 + t) * 2048 + h * 128 + j];
        } else {
            const int k = j - 128;
#pragma unroll
            for (int t = 0; t < 64; ++t) {
                const int chl = t * 16 + ((k >> 3) ^ (t & 15));
                x[t] = Bets[t] * Gam[t] * (float)Ksh[chl * 8 + (k & 7)];
            }
        }
#pragma unroll
        for (int t = 1; t < 64; ++t) {
            float acc = 0.f;
#pragma unroll
            for (int i = 0; i < t; ++i) acc = fmaf(Amat[t * 65 + i], x[i], acc);
            x[t] -= acc;
        }
        if (j < 128) {
#pragma unroll
            for (int t = 0; t < 64; t += 4) {
                half4 w4;
                w4[0] = (_Float16)x[t]; w4[1] = (_Float16)x[t + 1];
                w4[2] = (_Float16)x[t + 2]; w4[3] = (_Float16)x[t + 3];
                *(half4*)&Wtg[j * 64 + t] = w4;
            }
        } else {
            const int k = j - 128;
#pragma unroll
            for (int t = 0; t < 64; ++t) Ug[t * 128 + k] = (_Float16)x[t];
        }
    }

    {
        const float g63 = Gs[63];
        const int k = tid >> 1, cb = (tid & 1) * 32;
#pragma unroll
        for (int cc = 0; cc < 32; cc += 4) {
            half4 o4;
#pragma unroll
            for (int u = 0; u < 4; ++u) {
                const int ci = cb + cc + u;
                const int chl = ci * 16 + ((k >> 3) ^ (ci & 15));
                o4[u] = (_Float16)(expf(g63 - Gs[ci]) * (float)Ksh[chl * 8 + (k & 7)]);
            }
            *(half4*)&Khg[k * 64 + cb + cc] = o4;
        }
        const int cq = tid >> 2, kb = (tid & 3) * 4;
        const float gam = Gam[cq];
#pragma unroll
        for (int kc = 0; kc < 4; ++kc) {
            const int kcc = kb + kc;
            half8 q8 = *(const half8*)&Qsh[(cq * 16 + (kcc ^ (cq & 15))) * 8];
            half8 s8;
#pragma unroll
            for (int u = 0; u < 8; ++u) s8[u] = (_Float16)(gam * (float)q8[u]);
            *(half8*)&Qgg[cq * 128 + kcc * 8] = s8;
        }
        if (tid == 0) gamC[c * 16 + h] = Gam[63];
    }
}

// ---------------------------------------------------------------------------
// chunk_scan (unchanged): 32 blocks, LDS-staged operands.
// ---------------------------------------------------------------------------
__global__ __launch_bounds__(256) void chunk_scan(const _Float16* __restrict__ CH,
                                                  const float* __restrict__ gamC,
                                                  float* __restrict__ o) {
    const int h = blockIdx.x >> 1, vs = blockIdx.x & 1;
    const int tid = threadIdx.x, lane = tid & 63, wave = tid >> 6;
    const int l15 = lane & 15, quad = lane >> 4;
    const int vrow = wave * 16 + l15;

    __shared__ __align__(16) _Float16 Sh[8192];
    __shared__ __align__(16) _Float16 Dt[4096];
    __shared__ __align__(16) _Float16 LUg[8704];
    __shared__ __align__(16) _Float16 LWt[4608];
    __shared__ __align__(16) _Float16 LKh[9216];
    __shared__ __align__(16) _Float16 LQg[8704];
    __shared__ __align__(16) _Float16 LLg[4608];

    floatx4 Sacc[8];
#pragma unroll
    for (int kt = 0; kt < 8; ++kt) Sacc[kt] = 0;
    for (int i = tid; i < 1024; i += 256) *(int4*)&Sh[i * 8] = make_int4(0, 0, 0, 0);
    __syncthreads();

    for (int c = 0; c < 16; ++c) {
        const _Float16* CHb = CH + (size_t)(c * 16 + h) * 36864;
        {
            const int4* src = (const int4*)CHb;
#pragma unroll
            for (int i = 0; i < 4; ++i) {
                const int idx = tid + i * 256;
                *(int4*)&LUg[((idx >> 4) * 17 + (idx & 15)) * 8] = src[idx];
            }
        }
        {
            const int4* src = (const int4*)(CHb + 8192 + vs * 4096);
#pragma unroll
            for (int i = 0; i < 2; ++i) {
                const int idx = tid + i * 256;
                *(int4*)&LWt[((idx >> 3) * 9 + (idx & 7)) * 8] = src[idx];
            }
        }
        {
            const int4* src = (const int4*)(CHb + 16384);
#pragma unroll
            for (int i = 0; i < 4; ++i) {
                const int idx = tid + i * 256;
                *(int4*)&LKh[((idx >> 3) * 9 + (idx & 7)) * 8] = src[idx];
            }
        }
        {
            const int4* src = (const int4*)(CHb + 24576);
#pragma unroll
            for (int i = 0; i < 4; ++i) {
                const int idx = tid + i * 256;
                *(int4*)&LQg[((idx >> 4) * 17 + (idx & 15)) * 8] = src[idx];
            }
        }
        {
            const int4* src = (const int4*)(CHb + 32768);
#pragma unroll
            for (int i = 0; i < 2; ++i) {
                const int idx = tid + i * 256;
                *(int4*)&LLg[((idx >> 3) * 9 + (idx & 7)) * 8] = src[idx];
            }
        }
        __syncthreads();

        half8 bs[4];
#pragma unroll
        for (int ks = 0; ks < 4; ++ks) {
            const int kc = ks * 4 + quad;
            bs[ks] = *(const half8*)&Sh[(vrow * 16 + (kc ^ (vrow & 15))) * 8];
        }
#pragma unroll
        for (int ct = 0; ct < 4; ++ct) {
            floatx4 xa = {0.f, 0.f, 0.f, 0.f};
#pragma unroll
            for (int ks = 0; ks < 4; ++ks) {
                half8 af = *(const half8*)&LUg[((ct * 16 + l15) * 17 + ks * 4 + quad) * 8];
                xa = __builtin_amdgcn_mfma_f32_16x16x32_f16(af, bs[ks], xa, 0, 0, 0);
            }
            half4 w4 = *(const half4*)&LWt[(vrow * 9 + ct * 2 + (quad >> 1)) * 8 + (quad & 1) * 4];
            half4 d4;
#pragma unroll
            for (int r = 0; r < 4; ++r) d4[r] = (_Float16)((float)w4[r] - xa[r]);
            const int cc = ct * 2 + (quad >> 1);
            *(half4*)&Dt[(vrow * 8 + (cc ^ (vrow & 7))) * 8 + (quad & 1) * 4] = d4;
        }
        half8 bd[2];
#pragma unroll
        for (int cs = 0; cs < 2; ++cs) {
            const int cc = cs * 4 + quad;
            bd[cs] = *(const half8*)&Dt[(vrow * 8 + (cc ^ (vrow & 7))) * 8];
        }
#pragma unroll
        for (int ct = 0; ct < 4; ++ct) {
            floatx4 oa = {0.f, 0.f, 0.f, 0.f};
#pragma unroll
            for (int ks = 0; ks < 4; ++ks) {
                half8 af = *(const half8*)&LQg[((ct * 16 + l15) * 17 + ks * 4 + quad) * 8];
                oa = __builtin_amdgcn_mfma_f32_16x16x32_f16(af, bs[ks], oa, 0, 0, 0);
            }
#pragma unroll
            for (int cs = 0; cs < 2; ++cs) {
                half8 af = *(const half8*)&LLg[((ct * 16 + l15) * 9 + cs * 4 + quad) * 8];
                oa = __builtin_amdgcn_mfma_f32_16x16x32_f16(af, bd[cs], oa, 0, 0, 0);
            }
            const int tg = c * 64 + ct * 16 + quad * 4;
            const int col = h * 128 + vs * 64 + vrow;
#pragma unroll
            for (int r = 0; r < 4; ++r) o[(size_t)(tg + r) * 2048 + col] = oa[r];
        }
        const float gC = gamC[c * 16 + h];
#pragma unroll
        for (int kt = 0; kt < 8; ++kt) {
#pragma unroll
            for (int r = 0; r < 4; ++r) Sacc[kt][r] *= gC;
#pragma unroll
            for (int cs = 0; cs < 2; ++cs) {
                half8 af = *(const half8*)&LKh[((kt * 16 + l15) * 9 + cs * 4 + quad) * 8];
                Sacc[kt] = __builtin_amdgcn_mfma_f32_16x16x32_f16(af, bd[cs], Sacc[kt], 0, 0, 0);
            }
        }
#pragma unroll
        for (int kt = 0; kt < 8; ++kt) {
            const int kc = kt * 2 + (quad >> 1);
            half4 s4;
#pragma unroll
            for (int r = 0; r < 4; ++r) s4[r] = (_Float16)Sacc[kt][r];
            *(half4*)&Sh[(vrow * 16 + (kc ^ (vrow & 15))) * 8 + (quad & 1) * 4] = s4;
        }
        __syncthreads();
    }
}

// ---------------------------------------------------------------------------
// Gated RMSNorm: xf = o * silu(z); xn = xf * rsqrt(mean(xf^2)+eps) * w
// ---------------------------------------------------------------------------
__global__ __launch_bounds__(64) void gated_norm(const float* __restrict__ o,
                                                 const _Float16* __restrict__ qkvz,
                                                 const float* __restrict__ nw,
                                                 _Float16* __restrict__ xn) {
    const int b = blockIdx.x;
    const int t = b >> 4;
    const int vh = b & 15;
    const int kh = vh >> 1;
    const int r = vh & 1;
    const float* op = o + (size_t)t * 2048 + vh * 128;
    const _Float16* zp = qkvz + (size_t)t * QKVZ_N + kh * 768 + 512 + r * 128;
    const int j = threadIdx.x * 2;
    const float2 ov = *(const float2*)(op + j);
    const half2t zv = *(const half2t*)(zp + j);
    const float z0 = (float)zv[0], z1 = (float)zv[1];
    const float f0 = ov.x * z0 / (1.f + expf(-z0));
    const float f1 = ov.y * z1 / (1.f + expf(-z1));
    float ss = f0 * f0 + f1 * f1;
#pragma unroll
    for (int m = 1; m < 64; m <<= 1) ss += __shfl_xor(ss, m, 64);
    const float rs = rsqrtf(ss * (1.f / 128.f) + 1e-6f);
    _Float16* xp = xn + (size_t)t * 2048 + vh * 128;
    half2t y;
    y[0] = (_Float16)(f0 * rs * nw[j]);
    y[1] = (_Float16)(f1 * rs * nw[j + 1]);
    *(half2t*)(xp + j) = y;
}

// ---------------------------------------------------------------------------
extern "C" void kernel_launch(void* const* d_in, const int* in_sizes, int n_in,
                              void* d_out, int out_size, void* d_ws, size_t ws_size,
                              hipStream_t stream) {
    const float* hidden  = (const float*)d_in[0];
    const float* w_qkvz  = (const float*)d_in[1];
    const float* w_ba    = (const float*)d_in[2];
    const float* conv_w  = (const float*)d_in[3];
    const float* dt_bias = (const float*)d_in[4];
    const float* A_log   = (const float*)d_in[5];
    const float* norm_w  = (const float*)d_in[6];
    const float* w_out   = (const float*)d_in[7];
    float* out = (float*)d_out;

    // workspace layout (~63.2 MB), lifetime-based overlaps:
    //   hidden_h overlaps o        (hidden_h dead after qkvz GEMM)
    //   CH + xn_h overlap wqkvz_h  (wqkvz_h dead after qkvz GEMM)
    char* w = (char*)d_ws;
    _Float16*  qkvz_h = (_Float16*)(w);                 // 12,582,912 B (fp16)
    _Float16*  qch    = (_Float16*)(w + 12713984);      //  2,097,152 B
    _Float16*  kch    = (_Float16*)(w + 14811136);      //  2,097,152 B
    _Float16*  vch    = (_Float16*)(w + 16908288);      //  4,194,304 B
    float*     lgd    = (float*)(w + 21102592);         //     65,536 B
    float*     bet    = (float*)(w + 21168128);         //     65,536 B
    float*     gamC   = (float*)(w + 21233664);         //      4,096 B
    float*     o      = (float*)(w + 21237760);         //  8,388,608 B
    _Float16*  hid_h  = (_Float16*)(w + 21237760);      //  overlaps o
    _Float16*  wqk_h  = (_Float16*)(w + 29626368);      // 25,165,824 B
    _Float16*  CH     = (_Float16*)(w + 29626368);      //  overlaps wqk_h
    _Float16*  xn_h   = (_Float16*)(w + 29626368 + 18874368);  // after CH
    _Float16*  wout_h = (_Float16*)(w + 54792192);      //  8,388,608 B

    const int n0 = HIDDEN * T_LEN / 4;       //  524,288 float4s
    const int n1 = QKVZ_N * HIDDEN / 4;      // 3,145,728
    const int n2 = VAL_DIM * HIDDEN / 4;     // 1,048,576
    cvt3<<<(n0 + n1 + n2 + 255) / 256, 256, 0, stream>>>(hidden, hid_h, n0,
                                                         w_qkvz, wqk_h, n1,
                                                         w_out, wout_h, n2);

    gemm_h16<_Float16><<<16 * 48, 256, 0, stream>>>(hid_h, wqk_h, qkvz_h, 16, 48, HIDDEN);
    gemm_ba_gates<<<T_LEN, 256, 0, stream>>>(hidden, w_ba, dt_bias, A_log, lgd, bet);
    conv_silu_l2<<<T_LEN, 512, 0, stream>>>(qkvz_h, conv_w, qch, kch, vch);
    chunk_prep<<<256, 256, 0, stream>>>(qch, kch, vch, lgd, bet, CH, gamC);
    chunk_scan<<<32, 256, 0, stream>>>(CH, gamC, o);
    gated_norm<<<T_LEN * 16, 64, 0, stream>>>(o, qkvz_h, norm_w, xn_h);
    gemm_h16<float><<<16 * 16, 256, 0, stream>>>(xn_h, wout_h, out, 16, 16, HIDDEN);
}

// Round 2
// 298.922 us; speedup vs baseline: 1.0571x; 1.0483x over previous
//
#include <hip/hip_runtime.h>
#include <math.h>

// ---------------- problem constants ----------------
#define T_LEN   1024
#define HIDDEN  2048
#define QKVZ_N  6144   // 2*KEY_DIM + 2*VALUE_DIM
#define VAL_DIM 2048

typedef _Float16 half8 __attribute__((ext_vector_type(8)));
typedef _Float16 half4 __attribute__((ext_vector_type(4)));
typedef _Float16 half2t __attribute__((ext_vector_type(2)));
typedef float floatx4 __attribute__((ext_vector_type(4)));

__device__ __forceinline__ float sigmoidf_(float x) { return 1.f / (1.f + expf(-x)); }

// async global->LDS, 16B per lane; LDS dest = wave-uniform base + lane*16
__device__ __forceinline__ void gl_lds16(const _Float16* g, _Float16* l) {
    __builtin_amdgcn_global_load_lds(
        (const __attribute__((address_space(1))) void*)g,
        (__attribute__((address_space(3))) void*)l, 16, 0, 0);
}

// ---------------------------------------------------------------------------
// fused fp32 -> fp16 bulk convert of the three GEMM operands (1 launch)
// ---------------------------------------------------------------------------
__global__ __launch_bounds__(256) void cvt3(const float* __restrict__ s0, _Float16* __restrict__ d0, int n0,
                                            const float* __restrict__ s1, _Float16* __restrict__ d1, int n1,
                                            const float* __restrict__ s2, _Float16* __restrict__ d2, int n2) {
    int i = blockIdx.x * 256 + threadIdx.x;
    const float* s;
    _Float16* d;
    if (i < n0) { s = s0; d = d0; }
    else if (i < n0 + n1) { s = s1; d = d1; i -= n0; }
    else if (i < n0 + n1 + n2) { s = s2; d = d2; i -= n0 + n1; }
    else return;
    const float4 v = ((const float4*)s)[i];
    half4 h;
    h[0] = (_Float16)v.x; h[1] = (_Float16)v.y;
    h[2] = (_Float16)v.z; h[3] = (_Float16)v.w;
    *(half4*)&d[i * 4] = h;
}

// ---------------------------------------------------------------------------
// Pure-fp16 MFMA GEMM, 2-phase double-buffered pipeline (guide T3 minimum
// 2-phase template): C[M,N] = A[M,K]*W[N,K]^T.
// 64x128 tile, BK=64, 4 waves 2x2 (each 32x64 = 2x4x2 frags of 16x16x32).
// Per iteration: STAGE(next tile into buf^1) issued FIRST, then 12 ds_read
// + 16 MFMA on buf[cur], then ONE __syncthreads() whose vmcnt(0) drain is
// exactly the next tile's readiness -> loads fly during compute.  Barrier
// count per block 128 -> 32; MFMA per barrier 8 -> 16.
// LDS: (64+128) x 64 halves x 2 buffers = 48 KB -> 3 blocks/CU (qkvz grid
// 16x48 = 768 = exactly 3/CU; out grid 16x16 = 256 = 1/CU, pipeline hides
// latency even single-resident).
// Swizzle: row r stores global k-chunk kq at slot kq ^ (r&7) (involution,
// applied on the staging source addr AND the frag-read addr).  16 same-quad
// lanes (r = base..base+15) hit all 8 bank-groups 2x -> 2-way = free (m136).
// NOTE: SQ_LDS_BANK_CONFLICT ~= 8 x n_gl_lds16 is the structural write-side
// of global_load_lds (1024B/wave = 8 bank passes) -- not a real conflict.
// ---------------------------------------------------------------------------
template <typename OutT>
__global__ __launch_bounds__(256, 2) void gemm_h16(const _Float16* __restrict__ A,
                                                   const _Float16* __restrict__ W,
                                                   OutT* __restrict__ C,
                                                   int MB, int NB, int K) {
    const int N = NB * 128;
    const int l = blockIdx.x;
    const int x = l & 7;
    const int tt = l >> 3;
    const int mb = tt % MB;
    const int nb = x + 8 * (tt / MB);
    const int m0 = mb * 64, n0 = nb * 128;

    const int t = threadIdx.x;
    const int wave = t >> 6;
    const int lane = t & 63;
    const int wr = (wave >> 1) * 32;   // wave row offset (2 wave-rows of 32)
    const int wc = (wave & 1) * 64;    // wave col offset (2 wave-cols of 64)
    const int l15 = lane & 15;
    const int quad = lane >> 4;
    const int srow = lane >> 3;        // staging: row within 8-row group
    const int slot = lane & 7;         // staging: k-chunk slot 0..7

    __shared__ __align__(16) _Float16 Ah[2][4096];  //  64 rows x 64 k each
    __shared__ __align__(16) _Float16 Bh[2][8192];  // 128 rows x 64 k each

    floatx4 acc[2][4];
#pragma unroll
    for (int i = 0; i < 2; ++i)
#pragma unroll
        for (int j = 0; j < 4; ++j) acc[i][j] = 0;

    // stage one BK=64 tile into buffer `buf`; 6 gl_lds16 per wave.
    // LDS layout: row r = chunks [r*8, r*8+8); chunk kq lives at slot
    // kq ^ (r&7).  Source addr carries the inverse (same) permutation.
    auto stage = [&](int buf, int k0) {
#pragma unroll
        for (int g = 0; g < 2; ++g) {               // A: 16 rows/wave
            const int r = wave * 16 + g * 8 + srow;
            const int kc = slot ^ (r & 7);
            gl_lds16(A + (size_t)(m0 + r) * K + k0 + kc * 8,
                     &Ah[buf][(wave * 128 + g * 64) * 8]);
        }
#pragma unroll
        for (int g = 0; g < 4; ++g) {               // B: 32 rows/wave
            const int r = wave * 32 + g * 8 + srow;
            const int kc = slot ^ (r & 7);
            gl_lds16(W + (size_t)(n0 + r) * K + k0 + kc * 8,
                     &Bh[buf][(wave * 256 + g * 64) * 8]);
        }
    };

    const int NIT = K >> 6;   // 32 for K=2048
    stage(0, 0);
    __syncthreads();          // drains vmcnt(0): tile 0 resident
    int cur = 0;
    for (int it = 0; it < NIT; ++it) {
        if (it + 1 < NIT) stage(cur ^ 1, (it + 1) * 64);   // issue-early
        half8 af[2][2], bf[4][2];
#pragma unroll
        for (int mt = 0; mt < 2; ++mt)
#pragma unroll
            for (int ks = 0; ks < 2; ++ks) {
                const int m = wr + mt * 16 + l15;
                const int kq = ks * 4 + quad;
                af[mt][ks] = *(const half8*)&Ah[cur][(m * 8 + (kq ^ (m & 7))) * 8];
            }
#pragma unroll
        for (int nt = 0; nt < 4; ++nt)
#pragma unroll
            for (int ks = 0; ks < 2; ++ks) {
                const int n = wc + nt * 16 + l15;
                const int kq = ks * 4 + quad;
                bf[nt][ks] = *(const half8*)&Bh[cur][(n * 8 + (kq ^ (n & 7))) * 8];
            }
#pragma unroll
        for (int mt = 0; mt < 2; ++mt)
#pragma unroll
            for (int nt = 0; nt < 4; ++nt)
#pragma unroll
                for (int ks = 0; ks < 2; ++ks)
                    acc[mt][nt] = __builtin_amdgcn_mfma_f32_16x16x32_f16(
                        af[mt][ks], bf[nt][ks], acc[mt][nt], 0, 0, 0);
        if (it + 1 < NIT) {
            __syncthreads();   // drains next tile's loads; protects buf reuse
            cur ^= 1;
        }
    }
#pragma unroll
    for (int mt = 0; mt < 2; ++mt)
#pragma unroll
        for (int nt = 0; nt < 4; ++nt) {
            const int c = n0 + wc + nt * 16 + l15;
#pragma unroll
            for (int reg = 0; reg < 4; ++reg) {
                const int r = m0 + wr + mt * 16 + quad * 4 + reg;
                C[(size_t)r * N + c] = (OutT)acc[mt][nt][reg];
            }
        }
}

// ---------------------------------------------------------------------------
// ba projection fused with gates: per row m compute ba[32] in-block, then
// beta = sigmoid(b), lgd = -exp(A_log)*softplus(a+dt_bias).  1024 blocks.
// ---------------------------------------------------------------------------
__global__ __launch_bounds__(256) void gemm_ba_gates(const float* __restrict__ A,
                                                     const float* __restrict__ W,
                                                     const float* __restrict__ dt_bias,
                                                     const float* __restrict__ A_log,
                                                     float* __restrict__ lgd,
                                                     float* __restrict__ bet) {
    const int m = blockIdx.x;
    const int tid = threadIdx.x;
    const int kl = tid & 31;
    const int ng = tid >> 5;
    const float* Arow = A + (size_t)m * 2048;
    __shared__ float sba[32];

    float4 a4[16];
#pragma unroll
    for (int j = 0; j < 16; ++j)
        a4[j] = *(const float4*)(Arow + j * 128 + kl * 4);

#pragma unroll
    for (int nn = 0; nn < 4; ++nn) {
        const int n = nn * 8 + ng;
        const float* Wrow = W + (size_t)n * 2048;
        float acc = 0.f;
#pragma unroll
        for (int j = 0; j < 16; ++j) {
            const float4 w4 = *(const float4*)(Wrow + j * 128 + kl * 4);
            acc = fmaf(a4[j].x, w4.x, acc);
            acc = fmaf(a4[j].y, w4.y, acc);
            acc = fmaf(a4[j].z, w4.z, acc);
            acc = fmaf(a4[j].w, w4.w, acc);
        }
        acc += __shfl_xor(acc, 1, 64);
        acc += __shfl_xor(acc, 2, 64);
        acc += __shfl_xor(acc, 4, 64);
        acc += __shfl_xor(acc, 8, 64);
        acc += __shfl_xor(acc, 16, 64);
        if (kl == 0) sba[n] = acc;
    }
    __syncthreads();
    if (tid < 16) {
        const int vh = tid, kh = vh >> 1, r = vh & 1;
        const float b = sba[kh * 4 + r];
        const float a = sba[kh * 4 + 2 + r];
        bet[m * 16 + vh] = 1.f / (1.f + expf(-b));
        const float xx = a + dt_bias[vh];
        const float sp = (xx > 0.f) ? (xx + log1pf(expf(-xx))) : log1pf(expf(xx));
        lgd[m * 16 + vh] = -expf(A_log[vh]) * sp;
    }
}

// ---------------------------------------------------------------------------
// Depthwise causal conv1d (K=4) + SiLU + fused q/k L2-norm.
// One 512-thread block per timestep t; thread handles 8 consecutive channels
// (half8 loads per tap).  q/k heads are 128 channels = 16 consecutive lanes
// (wave-aligned), so the L2-norm reduce is a 4-level __shfl_xor; the
// 128^-0.5 q-scale is folded in.
// qkvz row layout per k-head block of 768: [q 128 | k 128 | v 256 | z 256]
// ---------------------------------------------------------------------------
__global__ __launch_bounds__(512) void conv_silu_l2(const _Float16* __restrict__ qkvz,
                                                    const float* __restrict__ conv_w,
                                                    _Float16* __restrict__ qc,
                                                    _Float16* __restrict__ kc,
                                                    _Float16* __restrict__ vc) {
    const int t = blockIdx.x;                 // timestep (uniform per block)
    const int c = threadIdx.x * 8;            // base channel, 0..4088
    int col;
    _Float16* dst;
    bool isqk;
    float extra = 1.f;
    if (c < 1024) {
        col = ((c >> 7) * 768) + (c & 127);
        dst = qc + t * 1024 + c;
        isqk = true;
        extra = 0.08838834764831845f;         // 128^-0.5 folded into q
    } else if (c < 2048) {
        const int cc = c - 1024;
        col = ((cc >> 7) * 768) + 128 + (cc & 127);
        dst = kc + t * 1024 + cc;
        isqk = true;
    } else {
        const int cc = c - 2048;
        col = ((cc >> 8) * 768) + 256 + (cc & 255);
        dst = vc + (size_t)t * 2048 + cc;
        isqk = false;
    }
    const size_t gb = (size_t)t * QKVZ_N + col;
    const half8 x3 = *(const half8*)(qkvz + gb);
    half8 x2, x1, x0;
    if (t >= 1) x2 = *(const half8*)(qkvz + gb - QKVZ_N);
    if (t >= 2) x1 = *(const half8*)(qkvz + gb - 2 * (size_t)QKVZ_N);
    if (t >= 3) x0 = *(const half8*)(qkvz + gb - 3 * (size_t)QKVZ_N);

    float y[8];
    float ss = 0.f;
#pragma unroll
    for (int u = 0; u < 8; ++u) {
        const float4 wv = *(const float4*)(conv_w + (c + u) * 4);
        float acc = (float)x3[u] * wv.w;
        if (t >= 1) acc = fmaf((float)x2[u], wv.z, acc);
        if (t >= 2) acc = fmaf((float)x1[u], wv.y, acc);
        if (t >= 3) acc = fmaf((float)x0[u], wv.x, acc);
        acc = acc * (1.f / (1.f + expf(-acc)));   // silu
        y[u] = acc;
        ss = fmaf(acc, acc, ss);
    }
    half8 ov;
    if (isqk) {
        // head = 128 channels = 16 lanes (lane groups aligned within wave)
        ss += __shfl_xor(ss, 1, 64);
        ss += __shfl_xor(ss, 2, 64);
        ss += __shfl_xor(ss, 4, 64);
        ss += __shfl_xor(ss, 8, 64);
        const float r = rsqrtf(ss + 1e-6f) * extra;
#pragma unroll
        for (int u = 0; u < 8; ++u) ov[u] = (_Float16)(y[u] * r);
    } else {
#pragma unroll
        for (int u = 0; u < 8; ++u) ov[u] = (_Float16)y[u];
    }
    *(half8*)dst = ov;
}

// ---------------------------------------------------------------------------
// chunk_prep (unchanged): per (chunk c, v-head h), fully parallel (256 blocks)
// ---------------------------------------------------------------------------
__global__ __launch_bounds__(256) void chunk_prep(
    const _Float16* __restrict__ qch, const _Float16* __restrict__ kch,
    const _Float16* __restrict__ vch, const float* __restrict__ lgd,
    const float* __restrict__ bet, _Float16* __restrict__ CH,
    float* __restrict__ gamC) {
    const int blk = blockIdx.x;
    const int c = blk >> 4, h = blk & 15, kh = h >> 1;
    const int c0 = c * 64;
    const int tid = threadIdx.x, lane = tid & 63, wave = tid >> 6;
    const int l15 = lane & 15, quad = lane >> 4;

    __shared__ __align__(16) _Float16 Ksh[8192];
    __shared__ __align__(16) _Float16 Qsh[8192];
    __shared__ float Amat[64 * 65];
    __shared__ float Gs[64], Bets[64], Gam[64];

    {
        const int t = tid >> 2, kc0 = (tid & 3) * 4;
        const size_t gb = (size_t)(c0 + t) * 1024 + kh * 128;
#pragma unroll
        for (int i = 0; i < 4; ++i) {
            const int kc = kc0 + i;
            half8 kv = *(const half8*)(kch + gb + kc * 8);
            half8 qv = *(const half8*)(qch + gb + kc * 8);
            const int chl = t * 16 + (kc ^ (t & 15));
            *(half8*)&Ksh[chl * 8] = kv;
            *(half8*)&Qsh[chl * 8] = qv;
        }
    }
    if (tid < 64) {
        float g = lgd[(size_t)(c0 + tid) * 16 + h];
#pragma unroll
        for (int off = 1; off < 64; off <<= 1) {
            float y = __shfl_up(g, off, 64);
            if (tid >= off) g += y;
        }
        Gs[tid] = g;
        Gam[tid] = expf(g);
        Bets[tid] = bet[(size_t)(c0 + tid) * 16 + h];
    }
    __syncthreads();

    _Float16* CHb = CH + (size_t)(c * 16 + h) * 36864;
    _Float16* Ug = CHb;
    _Float16* Wtg = CHb + 8192;
    _Float16* Khg = CHb + 16384;
    _Float16* Qgg = CHb + 24576;
    _Float16* Lg = CHb + 32768;

    {
        floatx4 accKK[4], accQK[4];
#pragma unroll
        for (int tt = 0; tt < 4; ++tt) { accKK[tt] = 0; accQK[tt] = 0; }
        half8 bfK[4];
#pragma unroll
        for (int ks = 0; ks < 4; ++ks) {
            const int i = wave * 16 + l15;
            const int kc = ks * 4 + quad;
            bfK[ks] = *(const half8*)&Ksh[(i * 16 + (kc ^ (i & 15))) * 8];
        }
#pragma unroll
        for (int tt = 0; tt < 4; ++tt) {
            const int t = tt * 16 + l15;
#pragma unroll
            for (int ks = 0; ks < 4; ++ks) {
                const int kc = ks * 4 + quad;
                const int chl = (t * 16 + (kc ^ (t & 15))) * 8;
                half8 afK = *(const half8*)&Ksh[chl];
                half8 afQ = *(const half8*)&Qsh[chl];
                accKK[tt] = __builtin_amdgcn_mfma_f32_16x16x32_f16(afK, bfK[ks], accKK[tt], 0, 0, 0);
                accQK[tt] = __builtin_amdgcn_mfma_f32_16x16x32_f16(afQ, bfK[ks], accQK[tt], 0, 0, 0);
            }
        }
        const int ii = wave * 16 + l15;
        const float Gi = Gs[ii];
#pragma unroll
        for (int tt = 0; tt < 4; ++tt)
#pragma unroll
            for (int r = 0; r < 4; ++r) {
                const int t = tt * 16 + quad * 4 + r;
                const float Gt = Gs[t];
                const float ratio = (ii <= t) ? expf(Gt - Gi) : 0.f;
                if (ii < t) Amat[t * 65 + ii] = Bets[t] * ratio * accKK[tt][r];
                Lg[t * 64 + ii] = (_Float16)((ii <= t) ? ratio * accQK[tt][r] : 0.f);
            }
    }
    __syncthreads();

    {
        const int j = tid;
        float x[64];
        if (j < 128) {
#pragma unroll
            for (int t = 0; t < 64; ++t)
                x[t] = Bets[t] * (float)vch[(size_t)(c0 + t) * 2048 + h * 128 + j];
        } else {
            const int k = j - 128;
#pragma unroll
            for (int t = 0; t < 64; ++t) {
                const int chl = t * 16 + ((k >> 3) ^ (t & 15));
                x[t] = Bets[t] * Gam[t] * (float)Ksh[chl * 8 + (k & 7)];
            }
        }
#pragma unroll
        for (int t = 1; t < 64; ++t) {
            float acc = 0.f;
#pragma unroll
            for (int i = 0; i < t; ++i) acc = fmaf(Amat[t * 65 + i], x[i], acc);
            x[t] -= acc;
        }
        if (j < 128) {
#pragma unroll
            for (int t = 0; t < 64; t += 4) {
                half4 w4;
                w4[0] = (_Float16)x[t]; w4[1] = (_Float16)x[t + 1];
                w4[2] = (_Float16)x[t + 2]; w4[3] = (_Float16)x[t + 3];
                *(half4*)&Wtg[j * 64 + t] = w4;
            }
        } else {
            const int k = j - 128;
#pragma unroll
            for (int t = 0; t < 64; ++t) Ug[t * 128 + k] = (_Float16)x[t];
        }
    }

    {
        const float g63 = Gs[63];
        const int k = tid >> 1, cb = (tid & 1) * 32;
#pragma unroll
        for (int cc = 0; cc < 32; cc += 4) {
            half4 o4;
#pragma unroll
            for (int u = 0; u < 4; ++u) {
                const int ci = cb + cc + u;
                const int chl = ci * 16 + ((k >> 3) ^ (ci & 15));
                o4[u] = (_Float16)(expf(g63 - Gs[ci]) * (float)Ksh[chl * 8 + (k & 7)]);
            }
            *(half4*)&Khg[k * 64 + cb + cc] = o4;
        }
        const int cq = tid >> 2, kb = (tid & 3) * 4;
        const float gam = Gam[cq];
#pragma unroll
        for (int kc = 0; kc < 4; ++kc) {
            const int kcc = kb + kc;
            half8 q8 = *(const half8*)&Qsh[(cq * 16 + (kcc ^ (cq & 15))) * 8];
            half8 s8;
#pragma unroll
            for (int u = 0; u < 8; ++u) s8[u] = (_Float16)(gam * (float)q8[u]);
            *(half8*)&Qgg[cq * 128 + kcc * 8] = s8;
        }
        if (tid == 0) gamC[c * 16 + h] = Gam[63];
    }
}

// ---------------------------------------------------------------------------
// chunk_scan (unchanged): 32 blocks, LDS-staged operands.
// ---------------------------------------------------------------------------
__global__ __launch_bounds__(256) void chunk_scan(const _Float16* __restrict__ CH,
                                                  const float* __restrict__ gamC,
                                                  float* __restrict__ o) {
    const int h = blockIdx.x >> 1, vs = blockIdx.x & 1;
    const int tid = threadIdx.x, lane = tid & 63, wave = tid >> 6;
    const int l15 = lane & 15, quad = lane >> 4;
    const int vrow = wave * 16 + l15;

    __shared__ __align__(16) _Float16 Sh[8192];
    __shared__ __align__(16) _Float16 Dt[4096];
    __shared__ __align__(16) _Float16 LUg[8704];
    __shared__ __align__(16) _Float16 LWt[4608];
    __shared__ __align__(16) _Float16 LKh[9216];
    __shared__ __align__(16) _Float16 LQg[8704];
    __shared__ __align__(16) _Float16 LLg[4608];

    floatx4 Sacc[8];
#pragma unroll
    for (int kt = 0; kt < 8; ++kt) Sacc[kt] = 0;
    for (int i = tid; i < 1024; i += 256) *(int4*)&Sh[i * 8] = make_int4(0, 0, 0, 0);
    __syncthreads();

    for (int c = 0; c < 16; ++c) {
        const _Float16* CHb = CH + (size_t)(c * 16 + h) * 36864;
        {
            const int4* src = (const int4*)CHb;
#pragma unroll
            for (int i = 0; i < 4; ++i) {
                const int idx = tid + i * 256;
                *(int4*)&LUg[((idx >> 4) * 17 + (idx & 15)) * 8] = src[idx];
            }
        }
        {
            const int4* src = (const int4*)(CHb + 8192 + vs * 4096);
#pragma unroll
            for (int i = 0; i < 2; ++i) {
                const int idx = tid + i * 256;
                *(int4*)&LWt[((idx >> 3) * 9 + (idx & 7)) * 8] = src[idx];
            }
        }
        {
            const int4* src = (const int4*)(CHb + 16384);
#pragma unroll
            for (int i = 0; i < 4; ++i) {
                const int idx = tid + i * 256;
                *(int4*)&LKh[((idx >> 3) * 9 + (idx & 7)) * 8] = src[idx];
            }
        }
        {
            const int4* src = (const int4*)(CHb + 24576);
#pragma unroll
            for (int i = 0; i < 4; ++i) {
                const int idx = tid + i * 256;
                *(int4*)&LQg[((idx >> 4) * 17 + (idx & 15)) * 8] = src[idx];
            }
        }
        {
            const int4* src = (const int4*)(CHb + 32768);
#pragma unroll
            for (int i = 0; i < 2; ++i) {
                const int idx = tid + i * 256;
                *(int4*)&LLg[((idx >> 3) * 9 + (idx & 7)) * 8] = src[idx];
            }
        }
        __syncthreads();

        half8 bs[4];
#pragma unroll
        for (int ks = 0; ks < 4; ++ks) {
            const int kc = ks * 4 + quad;
            bs[ks] = *(const half8*)&Sh[(vrow * 16 + (kc ^ (vrow & 15))) * 8];
        }
#pragma unroll
        for (int ct = 0; ct < 4; ++ct) {
            floatx4 xa = {0.f, 0.f, 0.f, 0.f};
#pragma unroll
            for (int ks = 0; ks < 4; ++ks) {
                half8 af = *(const half8*)&LUg[((ct * 16 + l15) * 17 + ks * 4 + quad) * 8];
                xa = __builtin_amdgcn_mfma_f32_16x16x32_f16(af, bs[ks], xa, 0, 0, 0);
            }
            half4 w4 = *(const half4*)&LWt[(vrow * 9 + ct * 2 + (quad >> 1)) * 8 + (quad & 1) * 4];
            half4 d4;
#pragma unroll
            for (int r = 0; r < 4; ++r) d4[r] = (_Float16)((float)w4[r] - xa[r]);
            const int cc = ct * 2 + (quad >> 1);
            *(half4*)&Dt[(vrow * 8 + (cc ^ (vrow & 7))) * 8 + (quad & 1) * 4] = d4;
        }
        half8 bd[2];
#pragma unroll
        for (int cs = 0; cs < 2; ++cs) {
            const int cc = cs * 4 + quad;
            bd[cs] = *(const half8*)&Dt[(vrow * 8 + (cc ^ (vrow & 7))) * 8];
        }
#pragma unroll
        for (int ct = 0; ct < 4; ++ct) {
            floatx4 oa = {0.f, 0.f, 0.f, 0.f};
#pragma unroll
            for (int ks = 0; ks < 4; ++ks) {
                half8 af = *(const half8*)&LQg[((ct * 16 + l15) * 17 + ks * 4 + quad) * 8];
                oa = __builtin_amdgcn_mfma_f32_16x16x32_f16(af, bs[ks], oa, 0, 0, 0);
            }
#pragma unroll
            for (int cs = 0; cs < 2; ++cs) {
                half8 af = *(const half8*)&LLg[((ct * 16 + l15) * 9 + cs * 4 + quad) * 8];
                oa = __builtin_amdgcn_mfma_f32_16x16x32_f16(af, bd[cs], oa, 0, 0, 0);
            }
            const int tg = c * 64 + ct * 16 + quad * 4;
            const int col = h * 128 + vs * 64 + vrow;
#pragma unroll
            for (int r = 0; r < 4; ++r) o[(size_t)(tg + r) * 2048 + col] = oa[r];
        }
        const float gC = gamC[c * 16 + h];
#pragma unroll
        for (int kt = 0; kt < 8; ++kt) {
#pragma unroll
            for (int r = 0; r < 4; ++r) Sacc[kt][r] *= gC;
#pragma unroll
            for (int cs = 0; cs < 2; ++cs) {
                half8 af = *(const half8*)&LKh[((kt * 16 + l15) * 9 + cs * 4 + quad) * 8];
                Sacc[kt] = __builtin_amdgcn_mfma_f32_16x16x32_f16(af, bd[cs], Sacc[kt], 0, 0, 0);
            }
        }
#pragma unroll
        for (int kt = 0; kt < 8; ++kt) {
            const int kc = kt * 2 + (quad >> 1);
            half4 s4;
#pragma unroll
            for (int r = 0; r < 4; ++r) s4[r] = (_Float16)Sacc[kt][r];
            *(half4*)&Sh[(vrow * 16 + (kc ^ (vrow & 15))) * 8 + (quad & 1) * 4] = s4;
        }
        __syncthreads();
    }
}

// ---------------------------------------------------------------------------
// Gated RMSNorm: xf = o * silu(z); xn = xf * rsqrt(mean(xf^2)+eps) * w
// ---------------------------------------------------------------------------
__global__ __launch_bounds__(64) void gated_norm(const float* __restrict__ o,
                                                 const _Float16* __restrict__ qkvz,
                                                 const float* __restrict__ nw,
                                                 _Float16* __restrict__ xn) {
    const int b = blockIdx.x;
    const int t = b >> 4;
    const int vh = b & 15;
    const int kh = vh >> 1;
    const int r = vh & 1;
    const float* op = o + (size_t)t * 2048 + vh * 128;
    const _Float16* zp = qkvz + (size_t)t * QKVZ_N + kh * 768 + 512 + r * 128;
    const int j = threadIdx.x * 2;
    const float2 ov = *(const float2*)(op + j);
    const half2t zv = *(const half2t*)(zp + j);
    const float z0 = (float)zv[0], z1 = (float)zv[1];
    const float f0 = ov.x * z0 / (1.f + expf(-z0));
    const float f1 = ov.y * z1 / (1.f + expf(-z1));
    float ss = f0 * f0 + f1 * f1;
#pragma unroll
    for (int m = 1; m < 64; m <<= 1) ss += __shfl_xor(ss, m, 64);
    const float rs = rsqrtf(ss * (1.f / 128.f) + 1e-6f);
    _Float16* xp = xn + (size_t)t * 2048 + vh * 128;
    half2t y;
    y[0] = (_Float16)(f0 * rs * nw[j]);
    y[1] = (_Float16)(f1 * rs * nw[j + 1]);
    *(half2t*)(xp + j) = y;
}

// ---------------------------------------------------------------------------
extern "C" void kernel_launch(void* const* d_in, const int* in_sizes, int n_in,
                              void* d_out, int out_size, void* d_ws, size_t ws_size,
                              hipStream_t stream) {
    const float* hidden  = (const float*)d_in[0];
    const float* w_qkvz  = (const float*)d_in[1];
    const float* w_ba    = (const float*)d_in[2];
    const float* conv_w  = (const float*)d_in[3];
    const float* dt_bias = (const float*)d_in[4];
    const float* A_log   = (const float*)d_in[5];
    const float* norm_w  = (const float*)d_in[6];
    const float* w_out   = (const float*)d_in[7];
    float* out = (float*)d_out;

    // workspace layout (~63.2 MB), lifetime-based overlaps:
    //   hidden_h overlaps o        (hidden_h dead after qkvz GEMM)
    //   CH + xn_h overlap wqkvz_h  (wqkvz_h dead after qkvz GEMM)
    char* w = (char*)d_ws;
    _Float16*  qkvz_h = (_Float16*)(w);                 // 12,582,912 B (fp16)
    _Float16*  qch    = (_Float16*)(w + 12713984);      //  2,097,152 B
    _Float16*  kch    = (_Float16*)(w + 14811136);      //  2,097,152 B
    _Float16*  vch    = (_Float16*)(w + 16908288);      //  4,194,304 B
    float*     lgd    = (float*)(w + 21102592);         //     65,536 B
    float*     bet    = (float*)(w + 21168128);         //     65,536 B
    float*     gamC   = (float*)(w + 21233664);         //      4,096 B
    float*     o      = (float*)(w + 21237760);         //  8,388,608 B
    _Float16*  hid_h  = (_Float16*)(w + 21237760);      //  overlaps o
    _Float16*  wqk_h  = (_Float16*)(w + 29626368);      // 25,165,824 B
    _Float16*  CH     = (_Float16*)(w + 29626368);      //  overlaps wqk_h
    _Float16*  xn_h   = (_Float16*)(w + 29626368 + 18874368);  // after CH
    _Float16*  wout_h = (_Float16*)(w + 54792192);      //  8,388,608 B

    const int n0 = HIDDEN * T_LEN / 4;       //  524,288 float4s
    const int n1 = QKVZ_N * HIDDEN / 4;      // 3,145,728
    const int n2 = VAL_DIM * HIDDEN / 4;     // 1,048,576
    cvt3<<<(n0 + n1 + n2 + 255) / 256, 256, 0, stream>>>(hidden, hid_h, n0,
                                                         w_qkvz, wqk_h, n1,
                                                         w_out, wout_h, n2);

    gemm_h16<_Float16><<<16 * 48, 256, 0, stream>>>(hid_h, wqk_h, qkvz_h, 16, 48, HIDDEN);
    gemm_ba_gates<<<T_LEN, 256, 0, stream>>>(hidden, w_ba, dt_bias, A_log, lgd, bet);
    conv_silu_l2<<<T_LEN, 512, 0, stream>>>(qkvz_h, conv_w, qch, kch, vch);
    chunk_prep<<<256, 256, 0, stream>>>(qch, kch, vch, lgd, bet, CH, gamC);
    chunk_scan<<<32, 256, 0, stream>>>(CH, gamC, o);
    gated_norm<<<T_LEN * 16, 64, 0, stream>>>(o, qkvz_h, norm_w, xn_h);
    gemm_h16<float><<<16 * 16, 256, 0, stream>>>(xn_h, wout_h, out, 16, 16, HIDDEN);
}

// Round 3
// 286.828 us; speedup vs baseline: 1.1016x; 1.0422x over previous
//
#include <hip/hip_runtime.h>
#include <math.h>

// ---------------- problem constants ----------------
#define T_LEN   1024
#define HIDDEN  2048
#define QKVZ_N  6144   // 2*KEY_DIM + 2*VALUE_DIM
#define VAL_DIM 2048

typedef _Float16 half8 __attribute__((ext_vector_type(8)));
typedef _Float16 half4 __attribute__((ext_vector_type(4)));
typedef _Float16 half2t __attribute__((ext_vector_type(2)));
typedef float floatx4 __attribute__((ext_vector_type(4)));

__device__ __forceinline__ float sigmoidf_(float x) { return 1.f / (1.f + expf(-x)); }

// async global->LDS, 16B per lane; LDS dest = wave-uniform base + lane*16
__device__ __forceinline__ void gl_lds16(const _Float16* g, _Float16* l) {
    __builtin_amdgcn_global_load_lds(
        (const __attribute__((address_space(1))) void*)g,
        (__attribute__((address_space(3))) void*)l, 16, 0, 0);
}

// ---------------------------------------------------------------------------
// fused fp32 -> fp16 bulk convert of the three GEMM operands (1 launch)
// ---------------------------------------------------------------------------
__global__ __launch_bounds__(256) void cvt3(const float* __restrict__ s0, _Float16* __restrict__ d0, int n0,
                                            const float* __restrict__ s1, _Float16* __restrict__ d1, int n1,
                                            const float* __restrict__ s2, _Float16* __restrict__ d2, int n2) {
    int i = blockIdx.x * 256 + threadIdx.x;
    const float* s;
    _Float16* d;
    if (i < n0) { s = s0; d = d0; }
    else if (i < n0 + n1) { s = s1; d = d1; i -= n0; }
    else if (i < n0 + n1 + n2) { s = s2; d = d2; i -= n0 + n1; }
    else return;
    const float4 v = ((const float4*)s)[i];
    half4 h;
    h[0] = (_Float16)v.x; h[1] = (_Float16)v.y;
    h[2] = (_Float16)v.z; h[3] = (_Float16)v.w;
    *(half4*)&d[i * 4] = h;
}

// ---------------------------------------------------------------------------
// Pure-fp16 MFMA GEMM, 2-phase double-buffered pipeline: C = A[M,K]*W[N,K]^T.
// 64x128 tile, BK=64, 4 waves 2x2.  STAGE(next) issued before compute(cur);
// single __syncthreads() per iter doubles as the vmcnt(0) drain.
// ---------------------------------------------------------------------------
template <typename OutT>
__global__ __launch_bounds__(256, 2) void gemm_h16(const _Float16* __restrict__ A,
                                                   const _Float16* __restrict__ W,
                                                   OutT* __restrict__ C,
                                                   int MB, int NB, int K) {
    const int N = NB * 128;
    const int l = blockIdx.x;
    const int x = l & 7;
    const int tt = l >> 3;
    const int mb = tt % MB;
    const int nb = x + 8 * (tt / MB);
    const int m0 = mb * 64, n0 = nb * 128;

    const int t = threadIdx.x;
    const int wave = t >> 6;
    const int lane = t & 63;
    const int wr = (wave >> 1) * 32;
    const int wc = (wave & 1) * 64;
    const int l15 = lane & 15;
    const int quad = lane >> 4;
    const int srow = lane >> 3;
    const int slot = lane & 7;

    __shared__ __align__(16) _Float16 Ah[2][4096];
    __shared__ __align__(16) _Float16 Bh[2][8192];

    floatx4 acc[2][4];
#pragma unroll
    for (int i = 0; i < 2; ++i)
#pragma unroll
        for (int j = 0; j < 4; ++j) acc[i][j] = 0;

    auto stage = [&](int buf, int k0) {
#pragma unroll
        for (int g = 0; g < 2; ++g) {
            const int r = wave * 16 + g * 8 + srow;
            const int kc = slot ^ (r & 7);
            gl_lds16(A + (size_t)(m0 + r) * K + k0 + kc * 8,
                     &Ah[buf][(wave * 128 + g * 64) * 8]);
        }
#pragma unroll
        for (int g = 0; g < 4; ++g) {
            const int r = wave * 32 + g * 8 + srow;
            const int kc = slot ^ (r & 7);
            gl_lds16(W + (size_t)(n0 + r) * K + k0 + kc * 8,
                     &Bh[buf][(wave * 256 + g * 64) * 8]);
        }
    };

    const int NIT = K >> 6;
    stage(0, 0);
    __syncthreads();
    int cur = 0;
    for (int it = 0; it < NIT; ++it) {
        if (it + 1 < NIT) stage(cur ^ 1, (it + 1) * 64);
        half8 af[2][2], bf[4][2];
#pragma unroll
        for (int mt = 0; mt < 2; ++mt)
#pragma unroll
            for (int ks = 0; ks < 2; ++ks) {
                const int m = wr + mt * 16 + l15;
                const int kq = ks * 4 + quad;
                af[mt][ks] = *(const half8*)&Ah[cur][(m * 8 + (kq ^ (m & 7))) * 8];
            }
#pragma unroll
        for (int nt = 0; nt < 4; ++nt)
#pragma unroll
            for (int ks = 0; ks < 2; ++ks) {
                const int n = wc + nt * 16 + l15;
                const int kq = ks * 4 + quad;
                bf[nt][ks] = *(const half8*)&Bh[cur][(n * 8 + (kq ^ (n & 7))) * 8];
            }
#pragma unroll
        for (int mt = 0; mt < 2; ++mt)
#pragma unroll
            for (int nt = 0; nt < 4; ++nt)
#pragma unroll
                for (int ks = 0; ks < 2; ++ks)
                    acc[mt][nt] = __builtin_amdgcn_mfma_f32_16x16x32_f16(
                        af[mt][ks], bf[nt][ks], acc[mt][nt], 0, 0, 0);
        if (it + 1 < NIT) {
            __syncthreads();
            cur ^= 1;
        }
    }
#pragma unroll
    for (int mt = 0; mt < 2; ++mt)
#pragma unroll
        for (int nt = 0; nt < 4; ++nt) {
            const int c = n0 + wc + nt * 16 + l15;
#pragma unroll
            for (int reg = 0; reg < 4; ++reg) {
                const int r = m0 + wr + mt * 16 + quad * 4 + reg;
                C[(size_t)r * N + c] = (OutT)acc[mt][nt][reg];
            }
        }
}

// ---------------------------------------------------------------------------
// ba projection fused with gates.  1024 blocks.
// ---------------------------------------------------------------------------
__global__ __launch_bounds__(256) void gemm_ba_gates(const float* __restrict__ A,
                                                     const float* __restrict__ W,
                                                     const float* __restrict__ dt_bias,
                                                     const float* __restrict__ A_log,
                                                     float* __restrict__ lgd,
                                                     float* __restrict__ bet) {
    const int m = blockIdx.x;
    const int tid = threadIdx.x;
    const int kl = tid & 31;
    const int ng = tid >> 5;
    const float* Arow = A + (size_t)m * 2048;
    __shared__ float sba[32];

    float4 a4[16];
#pragma unroll
    for (int j = 0; j < 16; ++j)
        a4[j] = *(const float4*)(Arow + j * 128 + kl * 4);

#pragma unroll
    for (int nn = 0; nn < 4; ++nn) {
        const int n = nn * 8 + ng;
        const float* Wrow = W + (size_t)n * 2048;
        float acc = 0.f;
#pragma unroll
        for (int j = 0; j < 16; ++j) {
            const float4 w4 = *(const float4*)(Wrow + j * 128 + kl * 4);
            acc = fmaf(a4[j].x, w4.x, acc);
            acc = fmaf(a4[j].y, w4.y, acc);
            acc = fmaf(a4[j].z, w4.z, acc);
            acc = fmaf(a4[j].w, w4.w, acc);
        }
        acc += __shfl_xor(acc, 1, 64);
        acc += __shfl_xor(acc, 2, 64);
        acc += __shfl_xor(acc, 4, 64);
        acc += __shfl_xor(acc, 8, 64);
        acc += __shfl_xor(acc, 16, 64);
        if (kl == 0) sba[n] = acc;
    }
    __syncthreads();
    if (tid < 16) {
        const int vh = tid, kh = vh >> 1, r = vh & 1;
        const float b = sba[kh * 4 + r];
        const float a = sba[kh * 4 + 2 + r];
        bet[m * 16 + vh] = 1.f / (1.f + expf(-b));
        const float xx = a + dt_bias[vh];
        const float sp = (xx > 0.f) ? (xx + log1pf(expf(-xx))) : log1pf(expf(xx));
        lgd[m * 16 + vh] = -expf(A_log[vh]) * sp;
    }
}

// ---------------------------------------------------------------------------
// Depthwise causal conv1d (K=4) + SiLU + fused q/k L2-norm.
// ---------------------------------------------------------------------------
__global__ __launch_bounds__(512) void conv_silu_l2(const _Float16* __restrict__ qkvz,
                                                    const float* __restrict__ conv_w,
                                                    _Float16* __restrict__ qc,
                                                    _Float16* __restrict__ kc,
                                                    _Float16* __restrict__ vc) {
    const int t = blockIdx.x;
    const int c = threadIdx.x * 8;
    int col;
    _Float16* dst;
    bool isqk;
    float extra = 1.f;
    if (c < 1024) {
        col = ((c >> 7) * 768) + (c & 127);
        dst = qc + t * 1024 + c;
        isqk = true;
        extra = 0.08838834764831845f;
    } else if (c < 2048) {
        const int cc = c - 1024;
        col = ((cc >> 7) * 768) + 128 + (cc & 127);
        dst = kc + t * 1024 + cc;
        isqk = true;
    } else {
        const int cc = c - 2048;
        col = ((cc >> 8) * 768) + 256 + (cc & 255);
        dst = vc + (size_t)t * 2048 + cc;
        isqk = false;
    }
    const size_t gb = (size_t)t * QKVZ_N + col;
    const half8 x3 = *(const half8*)(qkvz + gb);
    half8 x2, x1, x0;
    if (t >= 1) x2 = *(const half8*)(qkvz + gb - QKVZ_N);
    if (t >= 2) x1 = *(const half8*)(qkvz + gb - 2 * (size_t)QKVZ_N);
    if (t >= 3) x0 = *(const half8*)(qkvz + gb - 3 * (size_t)QKVZ_N);

    float y[8];
    float ss = 0.f;
#pragma unroll
    for (int u = 0; u < 8; ++u) {
        const float4 wv = *(const float4*)(conv_w + (c + u) * 4);
        float acc = (float)x3[u] * wv.w;
        if (t >= 1) acc = fmaf((float)x2[u], wv.z, acc);
        if (t >= 2) acc = fmaf((float)x1[u], wv.y, acc);
        if (t >= 3) acc = fmaf((float)x0[u], wv.x, acc);
        acc = acc * (1.f / (1.f + expf(-acc)));   // silu
        y[u] = acc;
        ss = fmaf(acc, acc, ss);
    }
    half8 ov;
    if (isqk) {
        ss += __shfl_xor(ss, 1, 64);
        ss += __shfl_xor(ss, 2, 64);
        ss += __shfl_xor(ss, 4, 64);
        ss += __shfl_xor(ss, 8, 64);
        const float r = rsqrtf(ss + 1e-6f) * extra;
#pragma unroll
        for (int u = 0; u < 8; ++u) ov[u] = (_Float16)(y[u] * r);
    } else {
#pragma unroll
        for (int u = 0; u < 8; ++u) ov[u] = (_Float16)y[u];
    }
    *(half8*)dst = ov;
}

// ---------------------------------------------------------------------------
// chunk_prep (unchanged): per (chunk c, v-head h), fully parallel (256 blocks)
// ---------------------------------------------------------------------------
__global__ __launch_bounds__(256) void chunk_prep(
    const _Float16* __restrict__ qch, const _Float16* __restrict__ kch,
    const _Float16* __restrict__ vch, const float* __restrict__ lgd,
    const float* __restrict__ bet, _Float16* __restrict__ CH,
    float* __restrict__ gamC) {
    const int blk = blockIdx.x;
    const int c = blk >> 4, h = blk & 15, kh = h >> 1;
    const int c0 = c * 64;
    const int tid = threadIdx.x, lane = tid & 63, wave = tid >> 6;
    const int l15 = lane & 15, quad = lane >> 4;

    __shared__ __align__(16) _Float16 Ksh[8192];
    __shared__ __align__(16) _Float16 Qsh[8192];
    __shared__ float Amat[64 * 65];
    __shared__ float Gs[64], Bets[64], Gam[64];

    {
        const int t = tid >> 2, kc0 = (tid & 3) * 4;
        const size_t gb = (size_t)(c0 + t) * 1024 + kh * 128;
#pragma unroll
        for (int i = 0; i < 4; ++i) {
            const int kc = kc0 + i;
            half8 kv = *(const half8*)(kch + gb + kc * 8);
            half8 qv = *(const half8*)(qch + gb + kc * 8);
            const int chl = t * 16 + (kc ^ (t & 15));
            *(half8*)&Ksh[chl * 8] = kv;
            *(half8*)&Qsh[chl * 8] = qv;
        }
    }
    if (tid < 64) {
        float g = lgd[(size_t)(c0 + tid) * 16 + h];
#pragma unroll
        for (int off = 1; off < 64; off <<= 1) {
            float y = __shfl_up(g, off, 64);
            if (tid >= off) g += y;
        }
        Gs[tid] = g;
        Gam[tid] = expf(g);
        Bets[tid] = bet[(size_t)(c0 + tid) * 16 + h];
    }
    __syncthreads();

    _Float16* CHb = CH + (size_t)(c * 16 + h) * 36864;
    _Float16* Ug = CHb;
    _Float16* Wtg = CHb + 8192;
    _Float16* Khg = CHb + 16384;
    _Float16* Qgg = CHb + 24576;
    _Float16* Lg = CHb + 32768;

    {
        floatx4 accKK[4], accQK[4];
#pragma unroll
        for (int tt = 0; tt < 4; ++tt) { accKK[tt] = 0; accQK[tt] = 0; }
        half8 bfK[4];
#pragma unroll
        for (int ks = 0; ks < 4; ++ks) {
            const int i = wave * 16 + l15;
            const int kc = ks * 4 + quad;
            bfK[ks] = *(const half8*)&Ksh[(i * 16 + (kc ^ (i & 15))) * 8];
        }
#pragma unroll
        for (int tt = 0; tt < 4; ++tt) {
            const int t = tt * 16 + l15;
#pragma unroll
            for (int ks = 0; ks < 4; ++ks) {
                const int kc = ks * 4 + quad;
                const int chl = (t * 16 + (kc ^ (t & 15))) * 8;
                half8 afK = *(const half8*)&Ksh[chl];
                half8 afQ = *(const half8*)&Qsh[chl];
                accKK[tt] = __builtin_amdgcn_mfma_f32_16x16x32_f16(afK, bfK[ks], accKK[tt], 0, 0, 0);
                accQK[tt] = __builtin_amdgcn_mfma_f32_16x16x32_f16(afQ, bfK[ks], accQK[tt], 0, 0, 0);
            }
        }
        const int ii = wave * 16 + l15;
        const float Gi = Gs[ii];
#pragma unroll
        for (int tt = 0; tt < 4; ++tt)
#pragma unroll
            for (int r = 0; r < 4; ++r) {
                const int t = tt * 16 + quad * 4 + r;
                const float Gt = Gs[t];
                const float ratio = (ii <= t) ? expf(Gt - Gi) : 0.f;
                if (ii < t) Amat[t * 65 + ii] = Bets[t] * ratio * accKK[tt][r];
                Lg[t * 64 + ii] = (_Float16)((ii <= t) ? ratio * accQK[tt][r] : 0.f);
            }
    }
    __syncthreads();

    {
        const int j = tid;
        float x[64];
        if (j < 128) {
#pragma unroll
            for (int t = 0; t < 64; ++t)
                x[t] = Bets[t] * (float)vch[(size_t)(c0 + t) * 2048 + h * 128 + j];
        } else {
            const int k = j - 128;
#pragma unroll
            for (int t = 0; t < 64; ++t) {
                const int chl = t * 16 + ((k >> 3) ^ (t & 15));
                x[t] = Bets[t] * Gam[t] * (float)Ksh[chl * 8 + (k & 7)];
            }
        }
#pragma unroll
        for (int t = 1; t < 64; ++t) {
            float acc = 0.f;
#pragma unroll
            for (int i = 0; i < t; ++i) acc = fmaf(Amat[t * 65 + i], x[i], acc);
            x[t] -= acc;
        }
        if (j < 128) {
#pragma unroll
            for (int t = 0; t < 64; t += 4) {
                half4 w4;
                w4[0] = (_Float16)x[t]; w4[1] = (_Float16)x[t + 1];
                w4[2] = (_Float16)x[t + 2]; w4[3] = (_Float16)x[t + 3];
                *(half4*)&Wtg[j * 64 + t] = w4;
            }
        } else {
            const int k = j - 128;
#pragma unroll
            for (int t = 0; t < 64; ++t) Ug[t * 128 + k] = (_Float16)x[t];
        }
    }

    {
        const float g63 = Gs[63];
        const int k = tid >> 1, cb = (tid & 1) * 32;
#pragma unroll
        for (int cc = 0; cc < 32; cc += 4) {
            half4 o4;
#pragma unroll
            for (int u = 0; u < 4; ++u) {
                const int ci = cb + cc + u;
                const int chl = ci * 16 + ((k >> 3) ^ (ci & 15));
                o4[u] = (_Float16)(expf(g63 - Gs[ci]) * (float)Ksh[chl * 8 + (k & 7)]);
            }
            *(half4*)&Khg[k * 64 + cb + cc] = o4;
        }
        const int cq = tid >> 2, kb = (tid & 3) * 4;
        const float gam = Gam[cq];
#pragma unroll
        for (int kc = 0; kc < 4; ++kc) {
            const int kcc = kb + kc;
            half8 q8 = *(const half8*)&Qsh[(cq * 16 + (kcc ^ (cq & 15))) * 8];
            half8 s8;
#pragma unroll
            for (int u = 0; u < 8; ++u) s8[u] = (_Float16)(gam * (float)q8[u]);
            *(half8*)&Qgg[cq * 128 + kcc * 8] = s8;
        }
        if (tid == 0) gamC[c * 16 + h] = Gam[63];
    }
}

// ---------------------------------------------------------------------------
// chunk_scan v2: 128 blocks (16 heads x 8 v-slices of 16), 256 threads.
// v-columns of the recurrence are independent -> 4x grid parallelism vs the
// old 32-block version.  Within a block the 4 waves SPLIT the work (was:
// replicate): wave w owns t-tile [w*16,w*16+16) for xa/Dt/o and k-slice
// [w*32,w*32+32) for the S-update (Sacc held in registers).  Per-wave MFMAs
// per chunk: 56 -> 14.  Shared operands (Ug/Qg/Lg/Kh/Wt) are loaded directly
// global->VGPR in MFMA fragment layout (no LDS round-trip), double-buffered
// across chunks (loads for c+1 issued before computing c -> L2 latency
// hidden).  Only S^T (4KB) and Dt (2KB) go through LDS; slot swizzle
// (even XOR of 2*l15) keeps both write and read at 2-way = free.
// Block decode h=blk&15, vsl=blk>>4: all 8 v-slices of a head share an XCD
// (blk%8 = h%8) so shared operands hit one L2.
// Exactly 2 barriers per chunk:
//   [bs reads | xa | Dt write]  B1  [oa | Sacc update | o,S' write]  B2
// ---------------------------------------------------------------------------
struct ScanOps {
    half8 aU[4];      // Ug[t][k] fragments  (xa A-operand)
    half8 aQ[4];      // Qg[t][k] fragments  (oa A-operand)
    half8 aL[2];      // Lg[t][t'] fragments
    half8 aK[2][2];   // Kh[k][t'] fragments (S-update A-operand)
    half4 wv;         // Wt[v][t] slice
    float gC;         // chunk decay gamma
};

__global__ __launch_bounds__(256) void chunk_scan(const _Float16* __restrict__ CH,
                                                  const float* __restrict__ gamC,
                                                  float* __restrict__ o) {
    const int h = blockIdx.x & 15;     // head
    const int vsl = blockIdx.x >> 4;   // v-slice of 16
    const int tid = threadIdx.x, lane = tid & 63, wave = tid >> 6;
    const int l15 = lane & 15, quad = lane >> 4;
    const int tw = wave * 16;          // wave's t-tile
    const int kw = wave * 32;          // wave's k-slice
    const int sKey = l15 << 1;         // even XOR key, 32-slot rows (S^T)
    const int dKey = (l15 << 1) & 14;  // even XOR key, 16-slot rows (Dt)

    __shared__ __align__(16) _Float16 Ssh[16 * 128];  // S^T [v16][k128], 4h slots
    __shared__ __align__(16) _Float16 Dsh[16 * 64];   // Dt  [v16][t64],  4h slots

    // zero state
    *(half8*)&Ssh[tid * 8] = half8{0, 0, 0, 0, 0, 0, 0, 0};
    floatx4 Sacc[2];
    Sacc[0] = 0; Sacc[1] = 0;
    __syncthreads();

    auto loadOps = [&](ScanOps& S, int c) {
        const _Float16* CHb = CH + (size_t)(c * 16 + h) * 36864;
#pragma unroll
        for (int ks = 0; ks < 4; ++ks) {
            S.aU[ks] = *(const half8*)(CHb + (tw + l15) * 128 + ks * 32 + quad * 8);
            S.aQ[ks] = *(const half8*)(CHb + 24576 + (tw + l15) * 128 + ks * 32 + quad * 8);
        }
#pragma unroll
        for (int cs = 0; cs < 2; ++cs) {
            S.aL[cs] = *(const half8*)(CHb + 32768 + (tw + l15) * 64 + cs * 32 + quad * 8);
#pragma unroll
            for (int kt = 0; kt < 2; ++kt)
                S.aK[kt][cs] = *(const half8*)(CHb + 16384 + (kw + kt * 16 + l15) * 64 + cs * 32 + quad * 8);
        }
        S.wv = *(const half4*)(CHb + 8192 + (vsl * 16 + l15) * 64 + tw + quad * 4);
        S.gC = gamC[c * 16 + h];
    };

    auto chunkBody = [&](const ScanOps& S, int c) {
        // ---- phase 1: bs reads, xa, Dt write ----
        half8 bs[4];
#pragma unroll
        for (int ks = 0; ks < 4; ++ks)
            bs[ks] = *(const half8*)&Ssh[(l15 * 32 + ((ks * 8 + quad * 2) ^ sKey)) * 4];
        floatx4 xa = {0.f, 0.f, 0.f, 0.f};
#pragma unroll
        for (int ks = 0; ks < 4; ++ks)
            xa = __builtin_amdgcn_mfma_f32_16x16x32_f16(S.aU[ks], bs[ks], xa, 0, 0, 0);
        half4 d4;
#pragma unroll
        for (int r = 0; r < 4; ++r) d4[r] = (_Float16)((float)S.wv[r] - xa[r]);
        *(half4*)&Dsh[(l15 * 16 + ((wave * 4 + quad) ^ dKey)) * 4] = d4;
        __syncthreads();   // Dt ready; all bs reads done before S' writes

        // ---- phase 2: oa, Sacc update, stores ----
        half8 bd[2];
#pragma unroll
        for (int cs = 0; cs < 2; ++cs)
            bd[cs] = *(const half8*)&Dsh[(l15 * 16 + ((cs * 8 + quad * 2) ^ dKey)) * 4];
        floatx4 oacc = {0.f, 0.f, 0.f, 0.f};
#pragma unroll
        for (int ks = 0; ks < 4; ++ks)
            oacc = __builtin_amdgcn_mfma_f32_16x16x32_f16(S.aQ[ks], bs[ks], oacc, 0, 0, 0);
#pragma unroll
        for (int cs = 0; cs < 2; ++cs)
            oacc = __builtin_amdgcn_mfma_f32_16x16x32_f16(S.aL[cs], bd[cs], oacc, 0, 0, 0);
#pragma unroll
        for (int kt = 0; kt < 2; ++kt) {
#pragma unroll
            for (int r = 0; r < 4; ++r) Sacc[kt][r] *= S.gC;
#pragma unroll
            for (int cs = 0; cs < 2; ++cs)
                Sacc[kt] = __builtin_amdgcn_mfma_f32_16x16x32_f16(S.aK[kt][cs], bd[cs], Sacc[kt], 0, 0, 0);
        }
        const int col = h * 128 + vsl * 16 + l15;
#pragma unroll
        for (int r = 0; r < 4; ++r)
            o[(size_t)(c * 64 + tw + quad * 4 + r) * 2048 + col] = oacc[r];
#pragma unroll
        for (int kt = 0; kt < 2; ++kt) {
            half4 s4;
#pragma unroll
            for (int r = 0; r < 4; ++r) s4[r] = (_Float16)Sacc[kt][r];
            *(half4*)&Ssh[(l15 * 32 + ((wave * 8 + kt * 4 + quad) ^ sKey)) * 4] = s4;
        }
        __syncthreads();   // S' ready; all bd reads done before next Dt write
    };

    ScanOps A_, B_;
    loadOps(A_, 0);
#pragma unroll 1
    for (int cc = 0; cc < 16; cc += 2) {
        loadOps(B_, cc + 1);                 // prefetch odd chunk
        chunkBody(A_, cc);
        if (cc + 2 < 16) loadOps(A_, cc + 2); // prefetch next even chunk
        chunkBody(B_, cc + 1);
    }
}

// ---------------------------------------------------------------------------
// Gated RMSNorm: xf = o * silu(z); xn = xf * rsqrt(mean(xf^2)+eps) * w
// ---------------------------------------------------------------------------
__global__ __launch_bounds__(64) void gated_norm(const float* __restrict__ o,
                                                 const _Float16* __restrict__ qkvz,
                                                 const float* __restrict__ nw,
                                                 _Float16* __restrict__ xn) {
    const int b = blockIdx.x;
    const int t = b >> 4;
    const int vh = b & 15;
    const int kh = vh >> 1;
    const int r = vh & 1;
    const float* op = o + (size_t)t * 2048 + vh * 128;
    const _Float16* zp = qkvz + (size_t)t * QKVZ_N + kh * 768 + 512 + r * 128;
    const int j = threadIdx.x * 2;
    const float2 ov = *(const float2*)(op + j);
    const half2t zv = *(const half2t*)(zp + j);
    const float z0 = (float)zv[0], z1 = (float)zv[1];
    const float f0 = ov.x * z0 / (1.f + expf(-z0));
    const float f1 = ov.y * z1 / (1.f + expf(-z1));
    float ss = f0 * f0 + f1 * f1;
#pragma unroll
    for (int m = 1; m < 64; m <<= 1) ss += __shfl_xor(ss, m, 64);
    const float rs = rsqrtf(ss * (1.f / 128.f) + 1e-6f);
    _Float16* xp = xn + (size_t)t * 2048 + vh * 128;
    half2t y;
    y[0] = (_Float16)(f0 * rs * nw[j]);
    y[1] = (_Float16)(f1 * rs * nw[j + 1]);
    *(half2t*)(xp + j) = y;
}

// ---------------------------------------------------------------------------
extern "C" void kernel_launch(void* const* d_in, const int* in_sizes, int n_in,
                              void* d_out, int out_size, void* d_ws, size_t ws_size,
                              hipStream_t stream) {
    const float* hidden  = (const float*)d_in[0];
    const float* w_qkvz  = (const float*)d_in[1];
    const float* w_ba    = (const float*)d_in[2];
    const float* conv_w  = (const float*)d_in[3];
    const float* dt_bias = (const float*)d_in[4];
    const float* A_log   = (const float*)d_in[5];
    const float* norm_w  = (const float*)d_in[6];
    const float* w_out   = (const float*)d_in[7];
    float* out = (float*)d_out;

    // workspace layout (~63.2 MB), lifetime-based overlaps:
    //   hidden_h overlaps o        (hidden_h dead after qkvz GEMM)
    //   CH + xn_h overlap wqkvz_h  (wqkvz_h dead after qkvz GEMM)
    char* w = (char*)d_ws;
    _Float16*  qkvz_h = (_Float16*)(w);                 // 12,582,912 B (fp16)
    _Float16*  qch    = (_Float16*)(w + 12713984);      //  2,097,152 B
    _Float16*  kch    = (_Float16*)(w + 14811136);      //  2,097,152 B
    _Float16*  vch    = (_Float16*)(w + 16908288);      //  4,194,304 B
    float*     lgd    = (float*)(w + 21102592);         //     65,536 B
    float*     bet    = (float*)(w + 21168128);         //     65,536 B
    float*     gamC   = (float*)(w + 21233664);         //      4,096 B
    float*     o      = (float*)(w + 21237760);         //  8,388,608 B
    _Float16*  hid_h  = (_Float16*)(w + 21237760);      //  overlaps o
    _Float16*  wqk_h  = (_Float16*)(w + 29626368);      // 25,165,824 B
    _Float16*  CH     = (_Float16*)(w + 29626368);      //  overlaps wqk_h
    _Float16*  xn_h   = (_Float16*)(w + 29626368 + 18874368);  // after CH
    _Float16*  wout_h = (_Float16*)(w + 54792192);      //  8,388,608 B

    const int n0 = HIDDEN * T_LEN / 4;       //  524,288 float4s
    const int n1 = QKVZ_N * HIDDEN / 4;      // 3,145,728
    const int n2 = VAL_DIM * HIDDEN / 4;     // 1,048,576
    cvt3<<<(n0 + n1 + n2 + 255) / 256, 256, 0, stream>>>(hidden, hid_h, n0,
                                                         w_qkvz, wqk_h, n1,
                                                         w_out, wout_h, n2);

    gemm_h16<_Float16><<<16 * 48, 256, 0, stream>>>(hid_h, wqk_h, qkvz_h, 16, 48, HIDDEN);
    gemm_ba_gates<<<T_LEN, 256, 0, stream>>>(hidden, w_ba, dt_bias, A_log, lgd, bet);
    conv_silu_l2<<<T_LEN, 512, 0, stream>>>(qkvz_h, conv_w, qch, kch, vch);
    chunk_prep<<<256, 256, 0, stream>>>(qch, kch, vch, lgd, bet, CH, gamC);
    chunk_scan<<<128, 256, 0, stream>>>(CH, gamC, o);
    gated_norm<<<T_LEN * 16, 64, 0, stream>>>(o, qkvz_h, norm_w, xn_h);
    gemm_h16<float><<<16 * 16, 256, 0, stream>>>(xn_h, wout_h, out, 16, 16, HIDDEN);
}